// Round 1
// baseline (769.752 us; speedup 1.0000x reference)
//
#include <hip/hip_runtime.h>
#include <math.h>

#define BB 2
#define QQ 4
#define NH 32
#define NKV 8
#define GRP 4      // NH / NKV
#define HD 128
#define DM 4096
#define KVN 4096
#define SL 4100    // KVN + QQ
#define RK 410     // top-k remain
#define NCOLS 6144 // 4096 (Wq) + 1024 (Wk) + 1024 (Wv)
#define NCHUNK 16
#define DCHUNK 256
#define SCHUNK 513
#define NSCHUNK 8
#define SCALE 0.08838834764831845f  // 1/sqrt(128)

// ---------------- rope tables (fp64 trig for accuracy) ----------------
__global__ __launch_bounds__(256) void k_tables(float* __restrict__ cos_t,
                                                float* __restrict__ sin_t) {
    int idx = blockIdx.x * 256 + threadIdx.x;
    if (idx >= SL * 64) return;
    int s = idx >> 6, i = idx & 63;
    double inv = pow(10000.0, -(double)i / 64.0);
    double f = (double)s * inv;
    cos_t[idx] = (float)cos(f);
    sin_t[idx] = (float)sin(f);
}

// ---------------- QKV projection: part[chunk][row8][col6144] ----------------
__global__ __launch_bounds__(256) void k_proj(const float* __restrict__ hs,
                                              const float* __restrict__ Wq,
                                              const float* __restrict__ Wk,
                                              const float* __restrict__ Wv,
                                              float* __restrict__ part) {
    int tid = threadIdx.x;
    int c = blockIdx.x * 256 + tid;   // 0..6143, per-block uniform matrix select
    int d0 = blockIdx.y * DCHUNK;
    const float* Wp; int ld, cc;
    if (c < 4096)      { Wp = Wq; ld = 4096; cc = c; }
    else if (c < 5120) { Wp = Wk; ld = 1024; cc = c - 4096; }
    else               { Wp = Wv; ld = 1024; cc = c - 5120; }
    float acc[8] = {0.f,0.f,0.f,0.f,0.f,0.f,0.f,0.f};
    const float* wp = Wp + (size_t)d0 * ld + cc;
    const float* hp = hs + d0;   // wave-uniform reads -> s_load
    for (int d = 0; d < DCHUNK; ++d) {
        float w = wp[(size_t)d * ld];
        #pragma unroll
        for (int r = 0; r < 8; ++r) acc[r] = fmaf(hp[r * DM + d], w, acc[r]);
    }
    float* pb = part + (size_t)blockIdx.y * (8 * NCOLS) + c;
    #pragma unroll
    for (int r = 0; r < 8; ++r) pb[(size_t)r * NCOLS] = acc[r];
}

// ---------------- reduce partials + rope q / new-k, copy new-v ----------------
__global__ __launch_bounds__(256) void k_rope(const float* __restrict__ part,
                                              const float* __restrict__ cos_t,
                                              const float* __restrict__ sin_t,
                                              float* __restrict__ q_r,
                                              float* __restrict__ kn_r,
                                              float* __restrict__ v_new) {
    int idx = blockIdx.x * 256 + threadIdx.x;
    if (idx >= 8 * 3072) return;
    int r = idx / 3072, t = idx % 3072;
    int b = r / QQ, qi = r % QQ;
    int pos = KVN + qi;
    int c_lo, c_hi;
    if (t < 2048)      { int h = t >> 6, i = t & 63; c_lo = h * 128 + i; c_hi = c_lo + 64; }
    else if (t < 2560) { int kh = (t - 2048) >> 6, i = (t - 2048) & 63; c_lo = 4096 + kh * 128 + i; c_hi = c_lo + 64; }
    else               { c_lo = 5120 + ((t - 2560) << 1); c_hi = c_lo + 1; }
    float x_lo = 0.f, x_hi = 0.f;
    for (int k = 0; k < NCHUNK; ++k) {
        const float* pb = part + (size_t)k * (8 * NCOLS) + (size_t)r * NCOLS;
        x_lo += pb[c_lo];
        x_hi += pb[c_hi];
    }
    if (t < 2048) {
        int h = t >> 6, i = t & 63;
        float cv = cos_t[pos * 64 + i], sv = sin_t[pos * 64 + i];
        float* dst = q_r + (((size_t)(b * NH + h) * QQ + qi) * HD);
        dst[i]      = x_lo * cv - x_hi * sv;
        dst[i + 64] = x_hi * cv + x_lo * sv;
    } else if (t < 2560) {
        int kh = (t - 2048) >> 6, i = (t - 2048) & 63;
        float cv = cos_t[pos * 64 + i], sv = sin_t[pos * 64 + i];
        float* dst = kn_r + (((size_t)(b * NKV + kh) * QQ + qi) * HD);
        dst[i]      = x_lo * cv - x_hi * sv;
        dst[i + 64] = x_hi * cv + x_lo * sv;
    } else {
        int cv = c_lo - 5120;           // 0..1022, even
        int kh = cv >> 7, dd = cv & 127;
        float* dst = v_new + (((size_t)(b * NKV + kh) * QQ + qi) * HD);
        dst[dd] = x_lo;
        dst[dd + 1] = x_hi;
    }
}

// ---------------- draft scores: wave per s, lane pairs (d, d+64) ----------------
__global__ __launch_bounds__(256) void k_score(const float* __restrict__ q_r,
                                               const float* __restrict__ kn_r,
                                               const float* __restrict__ k_cache,
                                               const float* __restrict__ cos_t,
                                               const float* __restrict__ sin_t,
                                               float* __restrict__ draft) {
    int bh = blockIdx.x;                 // b*NH + h
    int b = bh / NH, h = bh % NH;
    int tid = threadIdx.x, wid = tid >> 6, lane = tid & 63;
    int s0 = blockIdx.y * SCHUNK;
    int s1 = s0 + SCHUNK; if (s1 > SL) s1 = SL;
    float qlo[4], qhi[4];
    #pragma unroll
    for (int qi = 0; qi < 4; ++qi) {
        const float* qp = q_r + (((size_t)bh * QQ) + qi) * HD;
        qlo[qi] = qp[lane];
        qhi[qi] = qp[lane + 64];
    }
    for (int s = s0 + wid; s < s1; s += 4) {
        float kr_lo, kr_hi;
        if (s < KVN) {
            const float* kp = k_cache + ((size_t)bh * KVN + s) * HD;
            float k_lo = kp[lane], k_hi = kp[lane + 64];
            float cv = cos_t[s * 64 + lane], sv = sin_t[s * 64 + lane];
            kr_lo = k_lo * cv - k_hi * sv;
            kr_hi = k_hi * cv + k_lo * sv;
        } else {
            const float* kp = kn_r + (((size_t)(b * NKV + h / GRP) * QQ) + (s - KVN)) * HD;
            kr_lo = kp[lane];
            kr_hi = kp[lane + 64];
        }
        float p0 = kr_lo * qlo[0] + kr_hi * qhi[0];
        float p1 = kr_lo * qlo[1] + kr_hi * qhi[1];
        float p2 = kr_lo * qlo[2] + kr_hi * qhi[2];
        float p3 = kr_lo * qlo[3] + kr_hi * qhi[3];
        #pragma unroll
        for (int off = 32; off > 0; off >>= 1) {
            p0 += __shfl_down(p0, off);
            p1 += __shfl_down(p1, off);
            p2 += __shfl_down(p2, off);
            p3 += __shfl_down(p3, off);
        }
        if (lane == 0) {
            float* dp = draft + (size_t)bh * QQ * SL + s;
            dp[0 * SL] = p0; dp[1 * SL] = p1; dp[2 * SL] = p2; dp[3 * SL] = p3;
        }
    }
}

// ---------------- top-k threshold: radix select per row ----------------
__global__ __launch_bounds__(256) void k_topk(const float* __restrict__ draft,
                                              float* __restrict__ thr) {
    int row = blockIdx.x;               // 0..255
    const float* sc = draft + (size_t)row * SL;
    __shared__ unsigned int hist[256];
    __shared__ unsigned int s_prefix;
    __shared__ int s_remain;
    int tid = threadIdx.x;
    unsigned int prefix = 0;
    int remain = RK;
    for (int pass = 3; pass >= 0; --pass) {
        hist[tid] = 0;
        __syncthreads();
        int shift = pass * 8;
        for (int s = tid; s < SL; s += 256) {
            unsigned int u = __float_as_uint(sc[s]);
            unsigned int key = (u & 0x80000000u) ? ~u : (u | 0x80000000u);
            if (pass == 3 || (key >> (shift + 8)) == prefix)
                atomicAdd(&hist[(key >> shift) & 0xFFu], 1u);
        }
        __syncthreads();
        if (tid == 0) {
            int cum = 0, bsel = 0;
            for (int bb = 255; bb >= 0; --bb) {
                int c = (int)hist[bb];
                if (cum + c >= remain) { bsel = bb; break; }
                cum += c;
            }
            s_prefix = (prefix << 8) | (unsigned int)bsel;
            s_remain = remain - cum;
        }
        __syncthreads();
        prefix = s_prefix;
        remain = s_remain;
        __syncthreads();
    }
    if (tid == 0) {
        unsigned int u = (prefix & 0x80000000u) ? (prefix ^ 0x80000000u) : ~prefix;
        thr[row] = __uint_as_float(u);
    }
}

// ---------------- softmax stats: per-row max & sum over included ----------------
__global__ __launch_bounds__(256) void k_attn_stats(const float* __restrict__ draft,
                                                    const float* __restrict__ thr,
                                                    float* __restrict__ msum) {
    int bh = blockIdx.x;
    int tid = threadIdx.x;
    __shared__ float red[256];
    for (int qi = 0; qi < 4; ++qi) {
        int row = bh * QQ + qi;
        const float* sc = draft + (size_t)row * SL;
        float tq = thr[row];
        float lm = -3.4e38f;
        for (int s = tid; s < SL; s += 256) {
            float v = sc[s];
            if (v >= tq) lm = fmaxf(lm, v);
        }
        red[tid] = lm; __syncthreads();
        for (int st = 128; st > 0; st >>= 1) {
            if (tid < st) red[tid] = fmaxf(red[tid], red[tid + st]);
            __syncthreads();
        }
        float m = red[0];
        __syncthreads();
        float ls = 0.f;
        for (int s = tid; s < SL; s += 256) {
            float v = sc[s];
            if (v >= tq) ls += expf((v - m) * SCALE);
        }
        red[tid] = ls; __syncthreads();
        for (int st = 128; st > 0; st >>= 1) {
            if (tid < st) red[tid] += red[tid + st];
            __syncthreads();
        }
        if (tid == 0) { msum[row] = m; msum[256 + row] = red[0]; }
        __syncthreads();
    }
}

// ---------------- P @ V (chunked, normalized partials atomically added) ----------------
__global__ __launch_bounds__(256) void k_pv(const float* __restrict__ draft,
                                            const float* __restrict__ thr,
                                            const float* __restrict__ msum,
                                            const float* __restrict__ v_cache,
                                            const float* __restrict__ v_new,
                                            float* __restrict__ attn_acc) {
    int bh = blockIdx.x;
    int b = bh / NH, h = bh % NH;
    int tid = threadIdx.x, wid = tid >> 6, lane = tid & 63;
    int s0 = blockIdx.y * SCHUNK;
    int s1 = s0 + SCHUNK; if (s1 > SL) s1 = SL;
    float thr4[4], m4[4], isum4[4];
    #pragma unroll
    for (int qi = 0; qi < 4; ++qi) {
        int row = bh * QQ + qi;
        thr4[qi] = thr[row];
        m4[qi] = msum[row];
        isum4[qi] = 1.0f / msum[256 + row];
    }
    float acc[4][2] = {};
    const float* sc0 = draft + (size_t)bh * QQ * SL;
    for (int s = s0 + wid; s < s1; s += 4) {
        const float* vp = (s < KVN)
            ? v_cache + ((size_t)bh * KVN + s) * HD
            : v_new + (((size_t)(b * NKV + h / GRP) * QQ) + (s - KVN)) * HD;
        float v_lo = vp[lane], v_hi = vp[lane + 64];
        #pragma unroll
        for (int qi = 0; qi < 4; ++qi) {
            float v = sc0[(size_t)qi * SL + s];
            if (v >= thr4[qi]) {
                float w = expf((v - m4[qi]) * SCALE) * isum4[qi];
                acc[qi][0] += w * v_lo;
                acc[qi][1] += w * v_hi;
            }
        }
    }
    __shared__ float accs[4][4][128];   // [wave][q][d]
    #pragma unroll
    for (int qi = 0; qi < 4; ++qi) {
        accs[wid][qi][lane] = acc[qi][0];
        accs[wid][qi][lane + 64] = acc[qi][1];
    }
    __syncthreads();
    for (int e = tid; e < 512; e += 256) {
        int qi = e >> 7, dd = e & 127;
        float sum = accs[0][qi][dd] + accs[1][qi][dd] + accs[2][qi][dd] + accs[3][qi][dd];
        atomicAdd(&attn_acc[(size_t)(b * QQ + qi) * DM + h * HD + dd], sum);
    }
}

// ---------------- output projection: out += attn_flat @ Wo ----------------
__global__ __launch_bounds__(256) void k_oproj(const float* __restrict__ attn_flat,
                                               const float* __restrict__ Wo,
                                               float* __restrict__ out) {
    int tid = threadIdx.x;
    int c = blockIdx.x * 256 + tid;     // 0..4095
    int d0 = blockIdx.y * DCHUNK;
    float acc[8] = {0.f,0.f,0.f,0.f,0.f,0.f,0.f,0.f};
    const float* wp = Wo + (size_t)d0 * DM + c;
    const float* ap = attn_flat + d0;   // wave-uniform -> s_load
    for (int d = 0; d < DCHUNK; ++d) {
        float w = wp[(size_t)d * DM];
        #pragma unroll
        for (int r = 0; r < 8; ++r) acc[r] = fmaf(ap[r * DM + d], w, acc[r]);
    }
    #pragma unroll
    for (int r = 0; r < 8; ++r) atomicAdd(&out[(size_t)r * DM + c], acc[r]);
}

extern "C" void kernel_launch(void* const* d_in, const int* in_sizes, int n_in,
                              void* d_out, int out_size, void* d_ws, size_t ws_size,
                              hipStream_t stream) {
    const float* hs      = (const float*)d_in[0];
    const float* k_cache = (const float*)d_in[1];
    const float* v_cache = (const float*)d_in[2];
    const float* Wq      = (const float*)d_in[3];
    const float* Wk      = (const float*)d_in[4];
    const float* Wv      = (const float*)d_in[5];
    const float* Wo      = (const float*)d_in[6];
    float* out = (float*)d_out;
    float* ws  = (float*)d_ws;

    float* part  = ws;                 // 16*8*6144 = 786432
    float* q_r   = ws + 786432;        // 32768
    float* kn_r  = ws + 819200;        // 8192
    float* v_new = ws + 827392;        // 8192
    float* cos_t = ws + 835584;        // 262400
    float* sin_t = ws + 1097984;       // 262400
    float* draft = ws + 1360384;       // 256*4100 = 1049600
    float* thr   = ws + 2409984;       // 256
    float* msum  = ws + 2410240;       // 512
    float* attn  = ws + 2410752;       // 32768  (end: 2443520 floats ~ 9.8 MB)

    hipMemsetAsync(d_out, 0, (size_t)out_size * sizeof(float), stream);
    hipMemsetAsync(attn, 0, (size_t)BB * QQ * DM * sizeof(float), stream);

    k_tables<<<dim3((SL * 64 + 255) / 256), dim3(256), 0, stream>>>(cos_t, sin_t);
    k_proj<<<dim3(NCOLS / 256, NCHUNK), dim3(256), 0, stream>>>(hs, Wq, Wk, Wv, part);
    k_rope<<<dim3((8 * 3072 + 255) / 256), dim3(256), 0, stream>>>(part, cos_t, sin_t, q_r, kn_r, v_new);
    k_score<<<dim3(BB * NH, NSCHUNK), dim3(256), 0, stream>>>(q_r, kn_r, k_cache, cos_t, sin_t, draft);
    k_topk<<<dim3(BB * NH * QQ), dim3(256), 0, stream>>>(draft, thr);
    k_attn_stats<<<dim3(BB * NH), dim3(256), 0, stream>>>(draft, thr, msum);
    k_pv<<<dim3(BB * NH, NSCHUNK), dim3(256), 0, stream>>>(draft, thr, msum, v_cache, v_new, attn);
    k_oproj<<<dim3(DM / 256, NCHUNK), dim3(256), 0, stream>>>(attn, Wo, out);
}

// Round 2
// 483.737 us; speedup vs baseline: 1.5913x; 1.5913x over previous
//
#include <hip/hip_runtime.h>
#include <math.h>

#define BB 2
#define QQ 4
#define NH 32
#define NKV 8
#define GRP 4      // NH / NKV
#define HD 128
#define DM 4096
#define KVN 4096
#define SL 4100    // KVN + QQ
#define RK 410     // top-k remain
#define NCOLS 6144 // 4096 (Wq) + 1024 (Wk) + 1024 (Wv)
#define SCALE 0.08838834764831845f           // 1/sqrt(128)
#define K1 ((float)(0.08838834764831845 * 1.4426950408889634))  // SCALE*log2(e)
#define NSC 16
#define SCH 260    // 16*260 = 4160 >= 4100

// ---------------- rope tables (fp64 trig for accuracy) ----------------
__global__ __launch_bounds__(256) void k_tables(float* __restrict__ cos_t,
                                                float* __restrict__ sin_t) {
    int idx = blockIdx.x * 256 + threadIdx.x;
    if (idx >= SL * 64) return;
    int s = idx >> 6, i = idx & 63;
    double inv = pow(10000.0, -(double)i / 64.0);
    double f = (double)s * inv;
    cos_t[idx] = (float)cos(f);
    sin_t[idx] = (float)sin(f);
}

// ---------------- QKV projection: atomic partial sums into qkv[8][6144] ----------------
// grid (12, 32), block 128: block covers 512 cols x 128 depth
__global__ __launch_bounds__(128) void k_proj(const float* __restrict__ hs,
                                              const float* __restrict__ Wq,
                                              const float* __restrict__ Wk,
                                              const float* __restrict__ Wv,
                                              float* __restrict__ qkv) {
    int c4 = (blockIdx.x * 128 + threadIdx.x) * 4;
    int d0 = blockIdx.y * 128;
    const float* Wp; int ld, cc;
    if (c4 < 4096)      { Wp = Wq; ld = 4096; cc = c4; }
    else if (c4 < 5120) { Wp = Wk; ld = 1024; cc = c4 - 4096; }
    else                { Wp = Wv; ld = 1024; cc = c4 - 5120; }
    float acc[8][4] = {};
    const float* hp = hs + d0;
    const float* wp = Wp + (size_t)d0 * ld + cc;
    #pragma unroll 4
    for (int d = 0; d < 128; ++d) {
        float4 w = *(const float4*)(wp + (size_t)d * ld);
        #pragma unroll
        for (int r = 0; r < 8; ++r) {
            float hv = hp[r * DM + d];
            acc[r][0] = fmaf(hv, w.x, acc[r][0]);
            acc[r][1] = fmaf(hv, w.y, acc[r][1]);
            acc[r][2] = fmaf(hv, w.z, acc[r][2]);
            acc[r][3] = fmaf(hv, w.w, acc[r][3]);
        }
    }
    #pragma unroll
    for (int r = 0; r < 8; ++r)
        #pragma unroll
        for (int e = 0; e < 4; ++e)
            atomicAdd(&qkv[(size_t)r * NCOLS + c4 + e], acc[r][e]);
}

// ---------------- rope q / new-k, copy new-v ----------------
__global__ __launch_bounds__(256) void k_rope(const float* __restrict__ qkv,
                                              const float* __restrict__ cos_t,
                                              const float* __restrict__ sin_t,
                                              float* __restrict__ q_r,
                                              float* __restrict__ kn_r,
                                              float* __restrict__ v_new) {
    int idx = blockIdx.x * 256 + threadIdx.x;   // exactly 24576 = 96*256
    int r = idx / 3072, t = idx % 3072;
    int b = r / QQ, qi = r % QQ;
    int pos = KVN + qi;
    int c_lo, c_hi;
    if (t < 2048)      { int hh = t >> 6, i = t & 63; c_lo = hh * 128 + i; c_hi = c_lo + 64; }
    else if (t < 2560) { int kh = (t - 2048) >> 6, i = (t - 2048) & 63; c_lo = 4096 + kh * 128 + i; c_hi = c_lo + 64; }
    else               { c_lo = 5120 + ((t - 2560) << 1); c_hi = c_lo + 1; }
    float x_lo = qkv[(size_t)r * NCOLS + c_lo];
    float x_hi = qkv[(size_t)r * NCOLS + c_hi];
    if (t < 2048) {
        int hh = t >> 6, i = t & 63;
        float cv = cos_t[pos * 64 + i], sv = sin_t[pos * 64 + i];
        float* dst = q_r + (((size_t)(b * NH + hh) * QQ + qi) * HD);
        dst[i]      = x_lo * cv - x_hi * sv;
        dst[i + 64] = x_hi * cv + x_lo * sv;
    } else if (t < 2560) {
        int kh = (t - 2048) >> 6, i = (t - 2048) & 63;
        float cv = cos_t[pos * 64 + i], sv = sin_t[pos * 64 + i];
        float* dst = kn_r + (((size_t)(b * NKV + kh) * QQ + qi) * HD);
        dst[i]      = x_lo * cv - x_hi * sv;
        dst[i + 64] = x_hi * cv + x_lo * sv;
    } else {
        int cv = c_lo - 5120;
        int kh = cv >> 7, dd = cv & 127;
        float* dst = v_new + (((size_t)(b * NKV + kh) * QQ + qi) * HD);
        dst[dd] = x_lo;
        dst[dd + 1] = x_hi;
    }
}

__device__ __forceinline__ float dot8(float4 a, float4 b, float4 qa, float4 qb) {
    return a.x*qa.x + a.y*qa.y + a.z*qa.z + a.w*qa.w
         + b.x*qb.x + b.y*qb.y + b.z*qb.z + b.w*qb.w;
}

// ---------------- draft scores: 4 s-rows per wave-iter, width-16 reduce ----------------
// grid (64, NSC), block 256
__global__ __launch_bounds__(256) void k_score(const float* __restrict__ q_r,
                                               const float* __restrict__ kn_r,
                                               const float* __restrict__ k_cache,
                                               const float* __restrict__ cos_t,
                                               const float* __restrict__ sin_t,
                                               float* __restrict__ draft) {
    int bh = blockIdx.x, b = bh >> 5, hh = bh & 31;
    int tid = threadIdx.x, wave = tid >> 6, lane = tid & 63;
    int sgrp = lane >> 4, dq = (lane & 15) * 4;
    float4 qlo[4], qhi[4];
    const float* qb = q_r + (size_t)bh * QQ * HD;
    #pragma unroll
    for (int qi = 0; qi < 4; ++qi) {
        qlo[qi] = *(const float4*)(qb + qi * HD + dq);
        qhi[qi] = *(const float4*)(qb + qi * HD + dq + 64);
    }
    int s0 = blockIdx.y * SCH;
    int s1 = s0 + SCH; if (s1 > SL) s1 = SL;
    const float* knb = kn_r + ((size_t)(b * NKV + (hh >> 2)) * QQ) * HD;
    float* db = draft + (size_t)bh * QQ * SL;
    for (int s = s0 + wave * 4 + sgrp; s < s1; s += 16) {
        float4 lo, hi;
        if (s < KVN) {
            const float* kp = k_cache + ((size_t)bh * KVN + s) * HD;
            float4 klo = *(const float4*)(kp + dq);
            float4 khi = *(const float4*)(kp + dq + 64);
            float4 c4 = *(const float4*)(cos_t + (size_t)s * 64 + dq);
            float4 s4 = *(const float4*)(sin_t + (size_t)s * 64 + dq);
            lo.x = klo.x*c4.x - khi.x*s4.x;  hi.x = khi.x*c4.x + klo.x*s4.x;
            lo.y = klo.y*c4.y - khi.y*s4.y;  hi.y = khi.y*c4.y + klo.y*s4.y;
            lo.z = klo.z*c4.z - khi.z*s4.z;  hi.z = khi.z*c4.z + klo.z*s4.z;
            lo.w = klo.w*c4.w - khi.w*s4.w;  hi.w = khi.w*c4.w + klo.w*s4.w;
        } else {
            const float* kp = knb + (size_t)(s - KVN) * HD;
            lo = *(const float4*)(kp + dq);
            hi = *(const float4*)(kp + dq + 64);
        }
        float p0 = dot8(lo, hi, qlo[0], qhi[0]);
        float p1 = dot8(lo, hi, qlo[1], qhi[1]);
        float p2 = dot8(lo, hi, qlo[2], qhi[2]);
        float p3 = dot8(lo, hi, qlo[3], qhi[3]);
        #pragma unroll
        for (int off = 8; off; off >>= 1) {
            p0 += __shfl_down(p0, off, 16);
            p1 += __shfl_down(p1, off, 16);
            p2 += __shfl_down(p2, off, 16);
            p3 += __shfl_down(p3, off, 16);
        }
        if ((lane & 15) == 0) {
            db[0 * SL + s] = p0;
            db[1 * SL + s] = p1;
            db[2 * SL + s] = p2;
            db[3 * SL + s] = p3;
        }
    }
}

// ---------------- top-k threshold + softmax stats (fused) ----------------
__device__ __forceinline__ unsigned int okey(float f) {
    unsigned int u = __float_as_uint(f);
    return (u & 0x80000000u) ? ~u : (u | 0x80000000u);
}

// grid 256 (one row each), block 256
__global__ __launch_bounds__(256) void k_topk(const float* __restrict__ draft,
                                              float* __restrict__ thr,
                                              float* __restrict__ c2) {
    int row = blockIdx.x;
    const float4* sc4 = (const float4*)(draft + (size_t)row * SL);  // 1025 float4s
    __shared__ unsigned int hist[256];
    __shared__ float red[256];
    __shared__ unsigned int s_prefix;
    __shared__ int s_remain;
    int tid = threadIdx.x;
    unsigned int prefix = 0;
    int remain = RK;
    float lmax = -3.4e38f;
    // pass 3 (top byte) + row max
    hist[tid] = 0;
    __syncthreads();
    for (int i = tid; i < 1025; i += 256) {
        float4 v = sc4[i];
        lmax = fmaxf(fmaxf(lmax, fmaxf(v.x, v.y)), fmaxf(v.z, v.w));
        atomicAdd(&hist[okey(v.x) >> 24], 1u);
        atomicAdd(&hist[okey(v.y) >> 24], 1u);
        atomicAdd(&hist[okey(v.z) >> 24], 1u);
        atomicAdd(&hist[okey(v.w) >> 24], 1u);
    }
    red[tid] = lmax;
    __syncthreads();
    for (int st = 128; st > 0; st >>= 1) {
        if (tid < st) red[tid] = fmaxf(red[tid], red[tid + st]);
        __syncthreads();
    }
    float m = red[0];
    if (tid == 0) {
        int cum = 0, bsel = 0;
        for (int bb = 255; bb >= 0; --bb) {
            int c = (int)hist[bb];
            if (cum + c >= remain) { bsel = bb; break; }
            cum += c;
        }
        s_prefix = (unsigned int)bsel;
        s_remain = remain - cum;
    }
    __syncthreads();
    prefix = s_prefix; remain = s_remain;
    // passes 2..0
    for (int pass = 2; pass >= 0; --pass) {
        __syncthreads();
        hist[tid] = 0;
        __syncthreads();
        int shift = pass * 8;
        for (int i = tid; i < 1025; i += 256) {
            float4 v = sc4[i];
            unsigned int k0 = okey(v.x), k1 = okey(v.y), k2 = okey(v.z), k3 = okey(v.w);
            if ((k0 >> (shift + 8)) == prefix) atomicAdd(&hist[(k0 >> shift) & 0xFFu], 1u);
            if ((k1 >> (shift + 8)) == prefix) atomicAdd(&hist[(k1 >> shift) & 0xFFu], 1u);
            if ((k2 >> (shift + 8)) == prefix) atomicAdd(&hist[(k2 >> shift) & 0xFFu], 1u);
            if ((k3 >> (shift + 8)) == prefix) atomicAdd(&hist[(k3 >> shift) & 0xFFu], 1u);
        }
        __syncthreads();
        if (tid == 0) {
            int cum = 0, bsel = 0;
            for (int bb = 255; bb >= 0; --bb) {
                int c = (int)hist[bb];
                if (cum + c >= remain) { bsel = bb; break; }
                cum += c;
            }
            s_prefix = (prefix << 8) | (unsigned int)bsel;
            s_remain = remain - cum;
        }
        __syncthreads();
        prefix = s_prefix; remain = s_remain;
    }
    unsigned int u = (prefix & 0x80000000u) ? (prefix ^ 0x80000000u) : ~prefix;
    float thrv = __uint_as_float(u);
    // sum pass: sum of 2^((v - m)*K1) over included
    float ls = 0.f;
    for (int i = tid; i < 1025; i += 256) {
        float4 v = sc4[i];
        if (v.x >= thrv) ls += exp2f((v.x - m) * K1);
        if (v.y >= thrv) ls += exp2f((v.y - m) * K1);
        if (v.z >= thrv) ls += exp2f((v.z - m) * K1);
        if (v.w >= thrv) ls += exp2f((v.w - m) * K1);
    }
    __syncthreads();
    red[tid] = ls;
    __syncthreads();
    for (int st = 128; st > 0; st >>= 1) {
        if (tid < st) red[tid] += red[tid + st];
        __syncthreads();
    }
    if (tid == 0) {
        thr[row] = thrv;
        c2[row] = -m * K1 - log2f(red[0]);
    }
}

// ---------------- P @ V: 2 s-rows per wave-iter, register acc ----------------
// grid (64, NSC), block 256
__global__ __launch_bounds__(256) void k_pv(const float* __restrict__ draft,
                                            const float* __restrict__ thr,
                                            const float* __restrict__ c2,
                                            const float* __restrict__ v_cache,
                                            const float* __restrict__ v_new,
                                            float* __restrict__ attn_acc) {
    int bh = blockIdx.x, b = bh >> 5, hh = bh & 31;
    int tid = threadIdx.x, wave = tid >> 6, lane = tid & 63;
    int sh = lane >> 5, dq = (lane & 31) * 4;
    float thr4[4], c24[4];
    #pragma unroll
    for (int qi = 0; qi < 4; ++qi) {
        thr4[qi] = thr[bh * QQ + qi];
        c24[qi] = c2[bh * QQ + qi];
    }
    int s0 = blockIdx.y * SCH;
    int s1 = s0 + SCH; if (s1 > SL) s1 = SL;
    const float* sc0 = draft + (size_t)bh * QQ * SL;
    const float* vnb = v_new + ((size_t)(b * NKV + (hh >> 2)) * QQ) * HD;
    float acc[4][4] = {};
    for (int s = s0 + wave * 2 + sh; s < s1; s += 8) {
        const float* vp = (s < KVN) ? v_cache + ((size_t)bh * KVN + s) * HD
                                    : vnb + (size_t)(s - KVN) * HD;
        float4 v4 = *(const float4*)(vp + dq);
        #pragma unroll
        for (int qi = 0; qi < 4; ++qi) {
            float sv = sc0[(size_t)qi * SL + s];
            float w = exp2f(fmaf(sv, K1, c24[qi]));
            w = (sv >= thr4[qi]) ? w : 0.f;
            acc[qi][0] = fmaf(w, v4.x, acc[qi][0]);
            acc[qi][1] = fmaf(w, v4.y, acc[qi][1]);
            acc[qi][2] = fmaf(w, v4.z, acc[qi][2]);
            acc[qi][3] = fmaf(w, v4.w, acc[qi][3]);
        }
    }
    // combine the two half-wave s-streams
    #pragma unroll
    for (int qi = 0; qi < 4; ++qi)
        #pragma unroll
        for (int e = 0; e < 4; ++e)
            acc[qi][e] += __shfl_down(acc[qi][e], 32);
    __shared__ float accs[4][4][128];   // 8 KB: [wave][qi][d]
    if (lane < 32) {
        #pragma unroll
        for (int qi = 0; qi < 4; ++qi)
            *(float4*)&accs[wave][qi][dq] = make_float4(acc[qi][0], acc[qi][1], acc[qi][2], acc[qi][3]);
    }
    __syncthreads();
    for (int e = tid; e < 512; e += 256) {
        int qi = e >> 7, dd = e & 127;
        float sum = accs[0][qi][dd] + accs[1][qi][dd] + accs[2][qi][dd] + accs[3][qi][dd];
        atomicAdd(&attn_acc[(size_t)(b * QQ + qi) * DM + hh * HD + dd], sum);
    }
}

// ---------------- output projection: out += attn_flat @ Wo ----------------
// grid (8, 32), block 128
__global__ __launch_bounds__(128) void k_oproj(const float* __restrict__ attn_flat,
                                               const float* __restrict__ Wo,
                                               float* __restrict__ out) {
    int c4 = (blockIdx.x * 128 + threadIdx.x) * 4;
    int d0 = blockIdx.y * 128;
    float acc[8][4] = {};
    const float* ap = attn_flat + d0;
    const float* wp = Wo + (size_t)d0 * DM + c4;
    #pragma unroll 4
    for (int d = 0; d < 128; ++d) {
        float4 w = *(const float4*)(wp + (size_t)d * DM);
        #pragma unroll
        for (int r = 0; r < 8; ++r) {
            float hv = ap[r * DM + d];
            acc[r][0] = fmaf(hv, w.x, acc[r][0]);
            acc[r][1] = fmaf(hv, w.y, acc[r][1]);
            acc[r][2] = fmaf(hv, w.z, acc[r][2]);
            acc[r][3] = fmaf(hv, w.w, acc[r][3]);
        }
    }
    #pragma unroll
    for (int r = 0; r < 8; ++r)
        #pragma unroll
        for (int e = 0; e < 4; ++e)
            atomicAdd(&out[(size_t)r * DM + c4 + e], acc[r][e]);
}

extern "C" void kernel_launch(void* const* d_in, const int* in_sizes, int n_in,
                              void* d_out, int out_size, void* d_ws, size_t ws_size,
                              hipStream_t stream) {
    const float* hs      = (const float*)d_in[0];
    const float* k_cache = (const float*)d_in[1];
    const float* v_cache = (const float*)d_in[2];
    const float* Wq      = (const float*)d_in[3];
    const float* Wk      = (const float*)d_in[4];
    const float* Wv      = (const float*)d_in[5];
    const float* Wo      = (const float*)d_in[6];
    float* out = (float*)d_out;
    float* ws  = (float*)d_ws;

    float* qkv   = ws;                 // 49152
    float* q_r   = ws + 49152;         // 32768
    float* kn_r  = ws + 81920;         // 8192
    float* v_new = ws + 90112;         // 8192
    float* cos_t = ws + 98304;         // 262400
    float* sin_t = ws + 360704;        // 262400
    float* draft = ws + 623104;        // 1049600
    float* thr   = ws + 1672704;       // 256
    float* c2    = ws + 1672960;       // 256
    float* attn  = ws + 1673216;       // 32768 -> end 1705984 floats (~6.8 MB)

    hipMemsetAsync(d_out, 0, (size_t)out_size * sizeof(float), stream);
    hipMemsetAsync(qkv, 0, (size_t)8 * NCOLS * sizeof(float), stream);
    hipMemsetAsync(attn, 0, (size_t)BB * QQ * DM * sizeof(float), stream);

    k_tables<<<dim3((SL * 64 + 255) / 256), dim3(256), 0, stream>>>(cos_t, sin_t);
    k_proj<<<dim3(12, 32), dim3(128), 0, stream>>>(hs, Wq, Wk, Wv, qkv);
    k_rope<<<dim3(96), dim3(256), 0, stream>>>(qkv, cos_t, sin_t, q_r, kn_r, v_new);
    k_score<<<dim3(BB * NH, NSC), dim3(256), 0, stream>>>(q_r, kn_r, k_cache, cos_t, sin_t, draft);
    k_topk<<<dim3(BB * NH * QQ), dim3(256), 0, stream>>>(draft, thr, c2);
    k_pv<<<dim3(BB * NH, NSC), dim3(256), 0, stream>>>(draft, thr, c2, v_cache, v_new, attn);
    k_oproj<<<dim3(8, 32), dim3(128), 0, stream>>>(attn, Wo, out);
}